// Round 1
// baseline (379.790 us; speedup 1.0000x reference)
//
#include <hip/hip_runtime.h>
#include <hip/hip_bf16.h>

#define B_ 2
#define T_ 2048
#define D_ 1024
#define H_ 16
#define HD_ 64

typedef __attribute__((ext_vector_type(8))) short bf16x8;
typedef __attribute__((ext_vector_type(4))) float f32x4;

__device__ __forceinline__ short f2bf(float f) {
  unsigned int u = __builtin_bit_cast(unsigned int, f);
  u += 0x7fffu + ((u >> 16) & 1u);   // round-to-nearest-even
  return (short)(u >> 16);
}

__global__ void cast_f32_bf16(const float* __restrict__ in, short* __restrict__ out, int n) {
  int i = (blockIdx.x * blockDim.x + threadIdx.x) * 8;
  if (i + 7 >= n) return;
  float4 a = *(const float4*)(in + i);
  float4 b = *(const float4*)(in + i + 4);
  bf16x8 o;
  o[0] = f2bf(a.x); o[1] = f2bf(a.y); o[2] = f2bf(a.z); o[3] = f2bf(a.w);
  o[4] = f2bf(b.x); o[5] = f2bf(b.y); o[6] = f2bf(b.z); o[7] = f2bf(b.w);
  *(bf16x8*)(out + i) = o;
}

// C[M,N] = A[M,K] * B[N,K]^T  (both K-major bf16), fp32 accum.
// mode 0: out bf16 at [b,h,t,hd]   (m->(b,t), n->(h,hd))
// mode 1: out bf16 at [b,h,hd,t]   (V transposed)
// mode 2: out fp32 at [m*N+n]
// val = (acc + bias[n]) * scale
__launch_bounds__(256)
__global__ void gemm_nt(const short* __restrict__ A, const short* __restrict__ Bm,
                        const float* __restrict__ bias, float scale, int mode,
                        void* __restrict__ out, int M, int N, int K) {
  __shared__ short As[128 * 72];
  __shared__ short Bs[128 * 72];
  const int NB = N >> 7;
  const int bm = blockIdx.x / NB, bn = blockIdx.x % NB;
  const int tid = threadIdx.x, lane = tid & 63, w = tid >> 6;
  const int wr = w >> 1, wc = w & 1;
  const int lrow = lane & 15, lhi = lane >> 4;

  f32x4 acc[4][4] = {};

  for (int kt = 0; kt < K; kt += 64) {
#pragma unroll
    for (int i = 0; i < 4; ++i) {
      int L = tid + i * 256;
      int row = L >> 3, c8 = (L & 7) * 8;
      *(bf16x8*)(As + row * 72 + c8) =
          *(const bf16x8*)(A + (size_t)(bm * 128 + row) * K + kt + c8);
      *(bf16x8*)(Bs + row * 72 + c8) =
          *(const bf16x8*)(Bm + (size_t)(bn * 128 + row) * K + kt + c8);
    }
    __syncthreads();
    bf16x8 af[2][4], bfr[2][4];
#pragma unroll
    for (int ks = 0; ks < 2; ++ks)
#pragma unroll
      for (int i = 0; i < 4; ++i) {
        af[ks][i]  = *(const bf16x8*)(As + (wr * 64 + i * 16 + lrow) * 72 + ks * 32 + lhi * 8);
        bfr[ks][i] = *(const bf16x8*)(Bs + (wc * 64 + i * 16 + lrow) * 72 + ks * 32 + lhi * 8);
      }
#pragma unroll
    for (int ks = 0; ks < 2; ++ks)
#pragma unroll
      for (int i = 0; i < 4; ++i)
#pragma unroll
        for (int j = 0; j < 4; ++j)
          acc[i][j] = __builtin_amdgcn_mfma_f32_16x16x32_bf16(af[ks][i], bfr[ks][j],
                                                              acc[i][j], 0, 0, 0);
    __syncthreads();
  }

#pragma unroll
  for (int i = 0; i < 4; ++i)
#pragma unroll
    for (int j = 0; j < 4; ++j)
#pragma unroll
      for (int r = 0; r < 4; ++r) {
        int m = bm * 128 + wr * 64 + i * 16 + lhi * 4 + r;
        int n = bn * 128 + wc * 64 + j * 16 + lrow;
        float v = acc[i][j][r];
        if (bias) v += bias[n];
        v *= scale;
        if (mode == 2) {
          ((float*)out)[(size_t)m * N + n] = v;
        } else {
          int b = m >> 11, t = m & 2047, h = n >> 6, hd = n & 63;
          size_t idx = (mode == 0)
              ? ((size_t)(b * H_ + h) * T_ + t) * HD_ + hd
              : ((size_t)(b * H_ + h) * HD_ + hd) * T_ + t;
          ((short*)out)[idx] = f2bf(v);
        }
      }
}

// Flash attention. Q,K: [B,H,T,HD] bf16 (s^2 folded into Q). Vt: [B,H,HD,T] bf16.
// Out: bf16 [B*T, D] (= [b,t,h,hd]).
__launch_bounds__(256)
__global__ void attn_kernel(const short* __restrict__ Q, const short* __restrict__ K,
                            const short* __restrict__ Vt, short* __restrict__ Ob) {
  __shared__ short Plds[4][16 * 72];
  const int tid = threadIdx.x, lane = tid & 63, w = tid >> 6;
  const int lrow = lane & 15, lhi = lane >> 4;
  const int qb = blockIdx.x & 31;       // T/64
  const int bh = blockIdx.x >> 5;
  const int b = bh >> 4, h = bh & 15;

  const short* Qp = Q + ((size_t)bh * T_ + qb * 64 + w * 16) * HD_;
  bf16x8 qf[2];
#pragma unroll
  for (int ks = 0; ks < 2; ++ks)
    qf[ks] = *(const bf16x8*)(Qp + (size_t)lrow * HD_ + ks * 32 + lhi * 8);

  f32x4 oacc[4] = {};
  float mrow[4] = {-1e30f, -1e30f, -1e30f, -1e30f};
  float lsum[4] = {};
  const int qrow_base = qb * 64 + w * 16 + lhi * 4;  // + r

  for (int kb = 0; kb <= qb; ++kb) {
    // S = Q K^T (scale pre-folded)
    f32x4 s[4] = {};
    const short* Kp = K + ((size_t)bh * T_ + kb * 64) * HD_;
#pragma unroll
    for (int n = 0; n < 4; ++n)
#pragma unroll
      for (int ks = 0; ks < 2; ++ks) {
        bf16x8 kf = *(const bf16x8*)(Kp + (size_t)(n * 16 + lrow) * HD_ + ks * 32 + lhi * 8);
        s[n] = __builtin_amdgcn_mfma_f32_16x16x32_bf16(qf[ks], kf, s[n], 0, 0, 0);
      }
    // causal mask (only diagonal block)
    if (kb == qb) {
#pragma unroll
      for (int n = 0; n < 4; ++n) {
        int key = kb * 64 + n * 16 + lrow;
#pragma unroll
        for (int r = 0; r < 4; ++r)
          if (key > qrow_base + r) s[n][r] = -1e9f;
      }
    }
    // online softmax (rows live in 16-lane groups sharing lhi)
    float pv[4][4];
#pragma unroll
    for (int r = 0; r < 4; ++r) {
      float lm = fmaxf(fmaxf(s[0][r], s[1][r]), fmaxf(s[2][r], s[3][r]));
#pragma unroll
      for (int off = 1; off < 16; off <<= 1)
        lm = fmaxf(lm, __shfl_xor(lm, off));
      float mnew = fmaxf(mrow[r], lm);
      float c = __expf(mrow[r] - mnew);
      mrow[r] = mnew;
      float ls = 0.f;
#pragma unroll
      for (int n = 0; n < 4; ++n) {
        float p = __expf(s[n][r] - mnew);
        pv[n][r] = p;
        ls += p;
      }
#pragma unroll
      for (int off = 1; off < 16; off <<= 1)
        ls += __shfl_xor(ls, off);
      lsum[r] = lsum[r] * c + ls;
#pragma unroll
      for (int j = 0; j < 4; ++j)
        oacc[j][r] *= c;
    }
    // P (C/D layout) -> LDS -> A-fragment layout
    short* pl = Plds[w];
#pragma unroll
    for (int n = 0; n < 4; ++n)
#pragma unroll
      for (int r = 0; r < 4; ++r)
        pl[(lhi * 4 + r) * 72 + n * 16 + lrow] = f2bf(pv[n][r]);
    asm volatile("s_waitcnt lgkmcnt(0)" ::: "memory");
    bf16x8 pf[2];
#pragma unroll
    for (int ks = 0; ks < 2; ++ks)
      pf[ks] = *(const bf16x8*)(pl + lrow * 72 + ks * 32 + lhi * 8);
    // O += P V
    const short* Vp = Vt + (size_t)bh * HD_ * T_ + kb * 64;
#pragma unroll
    for (int j = 0; j < 4; ++j)
#pragma unroll
      for (int ks = 0; ks < 2; ++ks) {
        bf16x8 vf = *(const bf16x8*)(Vp + (size_t)(j * 16 + lrow) * T_ + ks * 32 + lhi * 8);
        oacc[j] = __builtin_amdgcn_mfma_f32_16x16x32_bf16(pf[ks], vf, oacc[j], 0, 0, 0);
      }
  }
  // epilogue: wv[b, t, h*64+d]
#pragma unroll
  for (int j = 0; j < 4; ++j)
#pragma unroll
    for (int r = 0; r < 4; ++r) {
      int t = qrow_base + r;
      int d = h * 64 + j * 16 + lrow;
      float v = oacc[j][r] / lsum[r];
      Ob[((size_t)(b * T_ + t)) * D_ + d] = f2bf(v);
    }
}

extern "C" void kernel_launch(void* const* d_in, const int* in_sizes, int n_in,
                              void* d_out, int out_size, void* d_ws, size_t ws_size,
                              hipStream_t stream) {
  const float* x  = (const float*)d_in[0];
  // d_in[1] = mask (causality applied analytically)
  const float* Wq = (const float*)d_in[2];
  const float* bq = (const float*)d_in[3];
  const float* Wk = (const float*)d_in[4];
  const float* Wv = (const float*)d_in[5];
  const float* bv = (const float*)d_in[6];
  const float* Wo = (const float*)d_in[7];
  const float* bo = (const float*)d_in[8];
  float* out = (float*)d_out;

  const int MT = B_ * T_;          // 4096
  short* xb  = (short*)d_ws;                 // [4096,1024]
  short* wqb = xb  + (size_t)MT * D_;        // [1024,1024]
  short* wkb = wqb + (size_t)D_ * D_;
  short* wvb = wkb + (size_t)D_ * D_;
  short* wob = wvb + (size_t)D_ * D_;
  short* Qb  = wob + (size_t)D_ * D_;        // [B,H,T,HD]
  short* Kb  = Qb  + (size_t)MT * D_;
  short* Vtb = Kb  + (size_t)MT * D_;        // [B,H,HD,T]
  short* Ab  = Vtb + (size_t)MT * D_;        // [4096,1024]

  // casts
  cast_f32_bf16<<<(MT * D_) / (256 * 8), 256, 0, stream>>>(x, xb, MT * D_);
  cast_f32_bf16<<<(D_ * D_) / (256 * 8), 256, 0, stream>>>(Wq, wqb, D_ * D_);
  cast_f32_bf16<<<(D_ * D_) / (256 * 8), 256, 0, stream>>>(Wk, wkb, D_ * D_);
  cast_f32_bf16<<<(D_ * D_) / (256 * 8), 256, 0, stream>>>(Wv, wvb, D_ * D_);
  cast_f32_bf16<<<(D_ * D_) / (256 * 8), 256, 0, stream>>>(Wo, wob, D_ * D_);

  const int grid_g = (MT / 128) * (D_ / 128);  // 256
  // Q = (x Wq^T + bq) * s^2  (s^2 = 1/sqrt(HD) = 0.125 folds both q,k scales)
  gemm_nt<<<grid_g, 256, 0, stream>>>(xb, wqb, bq, 0.125f, 0, Qb, MT, D_, D_);
  gemm_nt<<<grid_g, 256, 0, stream>>>(xb, wkb, nullptr, 1.0f, 0, Kb, MT, D_, D_);
  gemm_nt<<<grid_g, 256, 0, stream>>>(xb, wvb, bv, 1.0f, 1, Vtb, MT, D_, D_);

  attn_kernel<<<B_ * H_ * (T_ / 64), 256, 0, stream>>>(Qb, Kb, Vtb, Ab);

  gemm_nt<<<grid_g, 256, 0, stream>>>(Ab, wob, bo, 1.0f, 2, out, MT, D_, D_);
}

// Round 2
// 377.275 us; speedup vs baseline: 1.0067x; 1.0067x over previous
//
#include <hip/hip_runtime.h>
#include <hip/hip_bf16.h>

#define B_ 2
#define T_ 2048
#define D_ 1024
#define H_ 16
#define HD_ 64

typedef __attribute__((ext_vector_type(8))) short bf16x8;
typedef __attribute__((ext_vector_type(4))) short bf16x4;
typedef __attribute__((ext_vector_type(4))) float f32x4;

__device__ __forceinline__ short f2bf(float f) {
  unsigned int u = __builtin_bit_cast(unsigned int, f);
  u += 0x7fffu + ((u >> 16) & 1u);   // round-to-nearest-even
  return (short)(u >> 16);
}

__global__ void cast_f32_bf16(const float* __restrict__ in, short* __restrict__ out, int n) {
  int i = (blockIdx.x * blockDim.x + threadIdx.x) * 8;
  if (i + 7 >= n) return;
  float4 a = *(const float4*)(in + i);
  float4 b = *(const float4*)(in + i + 4);
  bf16x8 o;
  o[0] = f2bf(a.x); o[1] = f2bf(a.y); o[2] = f2bf(a.z); o[3] = f2bf(a.w);
  o[4] = f2bf(b.x); o[5] = f2bf(b.y); o[6] = f2bf(b.z); o[7] = f2bf(b.w);
  *(bf16x8*)(out + i) = o;
}

// C[M,N] = A[M,K] * B[N,K]^T  (both K-major bf16), fp32 accum.
// mode 0: out bf16 at [b,h,t,hd]   (m->(b,t), n->(h,hd))
// mode 1: out bf16 at [b,h,hd,t]   (V transposed)
// mode 2: out fp32 at [m*N+n]
// val = (acc + bias[n]) * scale
__launch_bounds__(256)
__global__ void gemm_nt(const short* __restrict__ A, const short* __restrict__ Bm,
                        const float* __restrict__ bias, float scale, int mode,
                        void* __restrict__ out, int M, int N, int K) {
  __shared__ short As[128 * 72];
  __shared__ short Bs[128 * 72];
  const int NB = N >> 7;
  const int bm = blockIdx.x / NB, bn = blockIdx.x % NB;
  const int tid = threadIdx.x, lane = tid & 63, w = tid >> 6;
  const int wr = w >> 1, wc = w & 1;
  const int lrow = lane & 15, lhi = lane >> 4;

  f32x4 acc[4][4] = {};

  for (int kt = 0; kt < K; kt += 64) {
#pragma unroll
    for (int i = 0; i < 4; ++i) {
      int L = tid + i * 256;
      int row = L >> 3, c8 = (L & 7) * 8;
      *(bf16x8*)(As + row * 72 + c8) =
          *(const bf16x8*)(A + (size_t)(bm * 128 + row) * K + kt + c8);
      *(bf16x8*)(Bs + row * 72 + c8) =
          *(const bf16x8*)(Bm + (size_t)(bn * 128 + row) * K + kt + c8);
    }
    __syncthreads();
    bf16x8 af[2][4], bfr[2][4];
#pragma unroll
    for (int ks = 0; ks < 2; ++ks)
#pragma unroll
      for (int i = 0; i < 4; ++i) {
        af[ks][i]  = *(const bf16x8*)(As + (wr * 64 + i * 16 + lrow) * 72 + ks * 32 + lhi * 8);
        bfr[ks][i] = *(const bf16x8*)(Bs + (wc * 64 + i * 16 + lrow) * 72 + ks * 32 + lhi * 8);
      }
#pragma unroll
    for (int ks = 0; ks < 2; ++ks)
#pragma unroll
      for (int i = 0; i < 4; ++i)
#pragma unroll
        for (int j = 0; j < 4; ++j)
          acc[i][j] = __builtin_amdgcn_mfma_f32_16x16x32_bf16(af[ks][i], bfr[ks][j],
                                                              acc[i][j], 0, 0, 0);
    __syncthreads();
  }

#pragma unroll
  for (int i = 0; i < 4; ++i)
#pragma unroll
    for (int j = 0; j < 4; ++j)
#pragma unroll
      for (int r = 0; r < 4; ++r) {
        int m = bm * 128 + wr * 64 + i * 16 + lhi * 4 + r;
        int n = bn * 128 + wc * 64 + j * 16 + lrow;
        float v = acc[i][j][r];
        if (bias) v += bias[n];
        v *= scale;
        if (mode == 2) {
          ((float*)out)[(size_t)m * N + n] = v;
        } else {
          int b = m >> 11, t = m & 2047, h = n >> 6, hd = n & 63;
          size_t idx = (mode == 0)
              ? ((size_t)(b * H_ + h) * T_ + t) * HD_ + hd
              : ((size_t)(b * H_ + h) * HD_ + hd) * T_ + t;
          ((short*)out)[idx] = f2bf(v);
        }
      }
}

// Flash attention, swapped-operand form.
// Q,K: [B,H,T,HD] bf16 (s^2 folded into Q). Vt: [B,H,HD,T] bf16.
// S^T = mfma(K,Q): lane (lrow,lhi) holds S[kk = n*16+lhi*4+r][q = lrow]
//   -> softmax row-reduce = 15 in-lane fmax + 2 shuffles (xor16/32).
// O^T = mfma(Vt,P): P read back from per-wave LDS as B-fragment (row=q).
// Out: bf16 [B*T, D] (= [b,t,h,hd]).
__launch_bounds__(256)
__global__ void attn_kernel(const short* __restrict__ Q, const short* __restrict__ K,
                            const short* __restrict__ Vt, short* __restrict__ Ob) {
  __shared__ short Plds[4][16 * 72];
  const int tid = threadIdx.x, lane = tid & 63, w = tid >> 6;
  const int lrow = lane & 15, lhi = lane >> 4;
  const int qb = 31 - (blockIdx.x & 31);   // heavy causal tiles dispatched first (LPT)
  const int bh = blockIdx.x >> 5;
  const int b = bh >> 4, h = bh & 15;

  const short* Qp = Q + ((size_t)bh * T_ + qb * 64 + w * 16) * HD_;
  bf16x8 qf[2];
#pragma unroll
  for (int ks = 0; ks < 2; ++ks)
    qf[ks] = *(const bf16x8*)(Qp + (size_t)lrow * HD_ + ks * 32 + lhi * 8);

  f32x4 oacc[4] = {};
  float mrun = -1e30f, lrun = 0.f;
  const int qrow = qb * 64 + w * 16 + lrow;    // this lane's q row
  short* pl = Plds[w];

  for (int kb = 0; kb <= qb; ++kb) {
    // S^T = K Q^T  (scale pre-folded into Q)
    f32x4 s[4] = {};
    const short* Kp = K + ((size_t)bh * T_ + kb * 64) * HD_;
#pragma unroll
    for (int n = 0; n < 4; ++n)
#pragma unroll
      for (int ks = 0; ks < 2; ++ks) {
        bf16x8 kf = *(const bf16x8*)(Kp + (size_t)(n * 16 + lrow) * HD_ + ks * 32 + lhi * 8);
        s[n] = __builtin_amdgcn_mfma_f32_16x16x32_bf16(kf, qf[ks], s[n], 0, 0, 0);
      }
    // preload V fragments (independent of softmax -> latency overlap)
    const short* Vp = Vt + (size_t)bh * HD_ * T_ + kb * 64;
    bf16x8 vf[4][2];
#pragma unroll
    for (int j = 0; j < 4; ++j)
#pragma unroll
      for (int ks = 0; ks < 2; ++ks)
        vf[j][ks] = *(const bf16x8*)(Vp + (size_t)(j * 16 + lrow) * T_ + ks * 32 + lhi * 8);

    // causal mask (diagonal block only): kk > q -> -inf
    if (kb == qb) {
#pragma unroll
      for (int n = 0; n < 4; ++n) {
        int kk = kb * 64 + n * 16 + lhi * 4;
#pragma unroll
        for (int r = 0; r < 4; ++r)
          if (kk + r > qrow) s[n][r] = -1e9f;
      }
    }

    // online softmax: each lane owns 16 scores of ONE q-row (q = lrow)
    float lm = s[0][0];
#pragma unroll
    for (int n = 0; n < 4; ++n)
#pragma unroll
      for (int r = 0; r < 4; ++r)
        lm = fmaxf(lm, s[n][r]);
    lm = fmaxf(lm, __shfl_xor(lm, 16));
    lm = fmaxf(lm, __shfl_xor(lm, 32));
    float mnew = fmaxf(mrun, lm);
    float c = __expf(mrun - mnew);
    mrun = mnew;
    float p[4][4];
    float ls = 0.f;
#pragma unroll
    for (int n = 0; n < 4; ++n)
#pragma unroll
      for (int r = 0; r < 4; ++r) {
        float e = __expf(s[n][r] - mnew);
        p[n][r] = e;
        ls += e;
      }
    ls += __shfl_xor(ls, 16);
    ls += __shfl_xor(ls, 32);
    lrun = lrun * c + ls;
#pragma unroll
    for (int j = 0; j < 4; ++j)
#pragma unroll
      for (int r = 0; r < 4; ++r)
        oacc[j][r] *= c;

    // P^T (C/D layout) -> LDS [q][kk] -> B-fragment (row=q)
#pragma unroll
    for (int n = 0; n < 4; ++n) {
      bf16x4 pk;
#pragma unroll
      for (int r = 0; r < 4; ++r) pk[r] = f2bf(p[n][r]);
      *(bf16x4*)(pl + lrow * 72 + n * 16 + lhi * 4) = pk;
    }
    asm volatile("s_waitcnt lgkmcnt(0)" ::: "memory");
    bf16x8 pf[2];
#pragma unroll
    for (int ks = 0; ks < 2; ++ks)
      pf[ks] = *(const bf16x8*)(pl + lrow * 72 + ks * 32 + lhi * 8);

    // O^T += V^T P^T : D[d][q]
#pragma unroll
    for (int j = 0; j < 4; ++j)
#pragma unroll
      for (int ks = 0; ks < 2; ++ks)
        oacc[j] = __builtin_amdgcn_mfma_f32_16x16x32_bf16(vf[j][ks], pf[ks], oacc[j], 0, 0, 0);
  }

  // epilogue: lane holds O[q=lrow][d = j*16+lhi*4+r]; wv[b, t, h*64+d]
  float inv = 1.0f / lrun;
  const int t = qb * 64 + w * 16 + lrow;
#pragma unroll
  for (int j = 0; j < 4; ++j) {
    bf16x4 ok;
#pragma unroll
    for (int r = 0; r < 4; ++r) ok[r] = f2bf(oacc[j][r] * inv);
    *(bf16x4*)(Ob + (size_t)(b * T_ + t) * D_ + h * 64 + j * 16 + lhi * 4) = ok;
  }
}

extern "C" void kernel_launch(void* const* d_in, const int* in_sizes, int n_in,
                              void* d_out, int out_size, void* d_ws, size_t ws_size,
                              hipStream_t stream) {
  const float* x  = (const float*)d_in[0];
  // d_in[1] = mask (causality applied analytically)
  const float* Wq = (const float*)d_in[2];
  const float* bq = (const float*)d_in[3];
  const float* Wk = (const float*)d_in[4];
  const float* Wv = (const float*)d_in[5];
  const float* bv = (const float*)d_in[6];
  const float* Wo = (const float*)d_in[7];
  const float* bo = (const float*)d_in[8];
  float* out = (float*)d_out;

  const int MT = B_ * T_;          // 4096
  short* xb  = (short*)d_ws;                 // [4096,1024]
  short* wqb = xb  + (size_t)MT * D_;        // [1024,1024]
  short* wkb = wqb + (size_t)D_ * D_;
  short* wvb = wkb + (size_t)D_ * D_;
  short* wob = wvb + (size_t)D_ * D_;
  short* Qb  = wob + (size_t)D_ * D_;        // [B,H,T,HD]
  short* Kb  = Qb  + (size_t)MT * D_;
  short* Vtb = Kb  + (size_t)MT * D_;        // [B,H,HD,T]
  short* Ab  = Vtb + (size_t)MT * D_;        // [4096,1024]

  // casts
  cast_f32_bf16<<<(MT * D_) / (256 * 8), 256, 0, stream>>>(x, xb, MT * D_);
  cast_f32_bf16<<<(D_ * D_) / (256 * 8), 256, 0, stream>>>(Wq, wqb, D_ * D_);
  cast_f32_bf16<<<(D_ * D_) / (256 * 8), 256, 0, stream>>>(Wk, wkb, D_ * D_);
  cast_f32_bf16<<<(D_ * D_) / (256 * 8), 256, 0, stream>>>(Wv, wvb, D_ * D_);
  cast_f32_bf16<<<(D_ * D_) / (256 * 8), 256, 0, stream>>>(Wo, wob, D_ * D_);

  const int grid_g = (MT / 128) * (D_ / 128);  // 256
  // Q = (x Wq^T + bq) * s^2  (s^2 = 1/sqrt(HD) = 0.125 folds both q,k scales)
  gemm_nt<<<grid_g, 256, 0, stream>>>(xb, wqb, bq, 0.125f, 0, Qb, MT, D_, D_);
  gemm_nt<<<grid_g, 256, 0, stream>>>(xb, wkb, nullptr, 1.0f, 0, Kb, MT, D_, D_);
  gemm_nt<<<grid_g, 256, 0, stream>>>(xb, wvb, bv, 1.0f, 1, Vtb, MT, D_, D_);

  attn_kernel<<<B_ * H_ * (T_ / 64), 256, 0, stream>>>(Qb, Kb, Vtb, Ab);

  gemm_nt<<<grid_g, 256, 0, stream>>>(Ab, wob, bo, 1.0f, 2, out, MT, D_, D_);
}

// Round 3
// 280.334 us; speedup vs baseline: 1.3548x; 1.3458x over previous
//
#include <hip/hip_runtime.h>
#include <hip/hip_bf16.h>

#define B_ 2
#define T_ 2048
#define D_ 1024
#define H_ 16
#define HD_ 64

typedef __attribute__((ext_vector_type(8))) short bf16x8;
typedef __attribute__((ext_vector_type(4))) short bf16x4;
typedef __attribute__((ext_vector_type(4))) float f32x4;
typedef __attribute__((ext_vector_type(4))) unsigned int u32x4;

__device__ __forceinline__ short f2bf(float f) {
  unsigned int u = __builtin_bit_cast(unsigned int, f);
  u += 0x7fffu + ((u >> 16) & 1u);   // round-to-nearest-even
  return (short)(u >> 16);
}

__device__ __forceinline__ unsigned cvtpk(float lo, float hi) {
  unsigned r;
  asm("v_cvt_pk_bf16_f32 %0, %1, %2" : "=v"(r) : "v"(lo), "v"(hi));
  return r;
}

__device__ __forceinline__ void gl16(const short* g, short* l) {
  __builtin_amdgcn_global_load_lds(
      (const __attribute__((address_space(1))) void*)g,
      (__attribute__((address_space(3))) void*)l, 16, 0, 0);
}

__global__ void cast_f32_bf16(const float* __restrict__ in, short* __restrict__ out, int n) {
  int i = (blockIdx.x * blockDim.x + threadIdx.x) * 8;
  if (i + 7 >= n) return;
  float4 a = *(const float4*)(in + i);
  float4 b = *(const float4*)(in + i + 4);
  bf16x8 o;
  o[0] = f2bf(a.x); o[1] = f2bf(a.y); o[2] = f2bf(a.z); o[3] = f2bf(a.w);
  o[4] = f2bf(b.x); o[5] = f2bf(b.y); o[6] = f2bf(b.z); o[7] = f2bf(b.w);
  *(bf16x8*)(out + i) = o;
}

// C[M,N] = A[M,K] * B[N,K]^T (bf16, K-major), fp32 accum. m97-style staging:
// global_load_lds width 16 into LINEAR LDS, BM=64, BN=128, BK=64.
// mode 0: out bf16 at [b,h,t,hd]; mode 1: out bf16 at [b,h,hd,t]; mode 2: fp32 [m*N+n]
__launch_bounds__(256)
__global__ void gemm_nt(const short* __restrict__ A, const short* __restrict__ Bm,
                        const float* __restrict__ bias, float scale, int mode,
                        void* __restrict__ out, int M, int N, int K) {
  __shared__ short As[64 * 64];
  __shared__ short Bs[128 * 64];
  const int NB = N >> 7;
  const int bm = blockIdx.x / NB, bn = blockIdx.x % NB;
  const int tid = threadIdx.x, lane = tid & 63, w = tid >> 6;
  const int wr = w >> 1, wc = w & 1;
  const int lrow = lane & 15, lhi = lane >> 4;
  const int srow = lane >> 3, scol = (lane & 7) * 8;   // staging: 8 rows x 128B per inst

  f32x4 acc[2][4] = {};
  const short* Ag0 = A + (size_t)(bm * 64 + w * 16 + srow) * K + scol;
  const short* Bg0 = Bm + (size_t)(bn * 128 + w * 32 + srow) * K + scol;

  for (int kt = 0; kt < K; kt += 64) {
#pragma unroll
    for (int i = 0; i < 2; ++i)
      gl16(Ag0 + kt + (size_t)i * 8 * K, As + (w * 16 + i * 8) * 64);
#pragma unroll
    for (int i = 0; i < 4; ++i)
      gl16(Bg0 + kt + (size_t)i * 8 * K, Bs + (w * 32 + i * 8) * 64);
    __syncthreads();
    bf16x8 af[2][2], bfr[2][4];
#pragma unroll
    for (int ks = 0; ks < 2; ++ks) {
#pragma unroll
      for (int i = 0; i < 2; ++i)
        af[ks][i] = *(const bf16x8*)(As + (wr * 32 + i * 16 + lrow) * 64 + ks * 32 + lhi * 8);
#pragma unroll
      for (int j = 0; j < 4; ++j)
        bfr[ks][j] = *(const bf16x8*)(Bs + (wc * 64 + j * 16 + lrow) * 64 + ks * 32 + lhi * 8);
    }
#pragma unroll
    for (int ks = 0; ks < 2; ++ks)
#pragma unroll
      for (int i = 0; i < 2; ++i)
#pragma unroll
        for (int j = 0; j < 4; ++j)
          acc[i][j] = __builtin_amdgcn_mfma_f32_16x16x32_bf16(af[ks][i], bfr[ks][j],
                                                              acc[i][j], 0, 0, 0);
    __syncthreads();
  }

#pragma unroll
  for (int i = 0; i < 2; ++i)
#pragma unroll
    for (int j = 0; j < 4; ++j) {
      const int m0 = bm * 64 + wr * 32 + i * 16 + lhi * 4;
      const int n = bn * 128 + wc * 64 + j * 16 + lrow;
      float bv = bias ? bias[n] : 0.f;
      if (mode == 1) {
        // 4 consecutive t at fixed (b,h,hd): vector store
        int b = m0 >> 11, t0 = m0 & 2047, h = n >> 6, hd = n & 63;
        bf16x4 ov;
#pragma unroll
        for (int r = 0; r < 4; ++r) ov[r] = f2bf((acc[i][j][r] + bv) * scale);
        *(bf16x4*)((short*)out + ((size_t)(b * H_ + h) * HD_ + hd) * T_ + t0) = ov;
      } else {
#pragma unroll
        for (int r = 0; r < 4; ++r) {
          int m = m0 + r;
          float v = (acc[i][j][r] + bv) * scale;
          if (mode == 2) {
            ((float*)out)[(size_t)m * N + n] = v;
          } else {
            int b = m >> 11, t = m & 2047, h = n >> 6, hd = n & 63;
            ((short*)out)[((size_t)(b * H_ + h) * T_ + t) * HD_ + hd] = f2bf(v);
          }
        }
      }
    }
}

// Flash attention, swapped-operand, register-only P, balanced strip pairs.
// Q,K: [B,H,T,HD] bf16 (s^2 folded into Q). Vt: [B,H,HD,T] bf16.
// Wave handles strips s0 and 127-s0 (16 q-rows each) -> 33 k-iters/wave, uniform.
// S^T = mfma(K,Q): lane holds S[k=n*16+lhi*4+r][q=lrow].
// PV uses custom k-slot bijection: pf[ks] = pack(p[2ks],p[2ks+1]); V loaded to match.
__launch_bounds__(256, 1)
__global__ void attn_kernel(const short* __restrict__ Q, const short* __restrict__ K,
                            const short* __restrict__ Vt, short* __restrict__ Ob) {
  const int tid = threadIdx.x, lane = tid & 63, w = tid >> 6;
  const int lrow = lane & 15, lhi = lane >> 4;
  const int bh = blockIdx.x >> 4;
  const int s0 = (blockIdx.x & 15) * 4 + w;   // strip 0..63; partner 127-s0
  const int b = bh >> 4, h = bh & 15;
  const short* Kbh = K + (size_t)bh * T_ * HD_;
  const short* Vbh = Vt + (size_t)bh * HD_ * T_;

  for (int half = 0; half < 2; ++half) {
    const int st = half ? (127 - s0) : s0;
    const int qb = st >> 2;                   // k-blocks 0..qb
    const int qrow = st * 16 + lrow;

    bf16x8 qf[2];
#pragma unroll
    for (int ks = 0; ks < 2; ++ks)
      qf[ks] = *(const bf16x8*)(Q + ((size_t)bh * T_ + st * 16 + lrow) * HD_ + ks * 32 + lhi * 8);

    f32x4 oacc[4] = {};
    float mrun = -3e38f, lrun = 0.f;

    // prologue: S(0)
    f32x4 s[4] = {};
#pragma unroll
    for (int n = 0; n < 4; ++n)
#pragma unroll
      for (int ks = 0; ks < 2; ++ks) {
        bf16x8 kf = *(const bf16x8*)(Kbh + (size_t)(n * 16 + lrow) * HD_ + ks * 32 + lhi * 8);
        s[n] = __builtin_amdgcn_mfma_f32_16x16x32_bf16(kf, qf[ks], s[n], 0, 0, 0);
      }

    for (int kb = 0; kb <= qb; ++kb) {
      const bool last_kb = (kb == qb);
      // prefetch next K tile fragments (independent of everything below)
      bf16x8 kfn[4][2];
      if (!last_kb) {
        const short* Kp = Kbh + (size_t)(kb + 1) * 64 * HD_;
#pragma unroll
        for (int n = 0; n < 4; ++n)
#pragma unroll
          for (int ks = 0; ks < 2; ++ks)
            kfn[n][ks] = *(const bf16x8*)(Kp + (size_t)(n * 16 + lrow) * HD_ + ks * 32 + lhi * 8);
      }
      // V fragments for kb with the custom k-slot mapping:
      // slot (lhi,e,ks) -> k = (2ks+(e>>2))*16 + lhi*4 + (e&3)
      bf16x8 vf[4][2];
#pragma unroll
      for (int j = 0; j < 4; ++j) {
        const short* vr = Vbh + (size_t)(j * 16 + lrow) * T_ + kb * 64 + lhi * 4;
#pragma unroll
        for (int ks = 0; ks < 2; ++ks) {
          bf16x4 lo = *(const bf16x4*)(vr + ks * 32);
          bf16x4 hi = *(const bf16x4*)(vr + ks * 32 + 16);
          bf16x8 v;
          v[0] = lo[0]; v[1] = lo[1]; v[2] = lo[2]; v[3] = lo[3];
          v[4] = hi[0]; v[5] = hi[1]; v[6] = hi[2]; v[7] = hi[3];
          vf[j][ks] = v;
        }
      }
      // causal mask on diagonal block
      if (last_kb) {
        const int kk0 = kb * 64 + lhi * 4;
#pragma unroll
        for (int n = 0; n < 4; ++n)
#pragma unroll
          for (int r = 0; r < 4; ++r)
            if (kk0 + n * 16 + r > qrow) s[n][r] = -1e9f;
      }
      // row max: 16 in-lane (tree) + 2 shuffles
      float m0 = fmaxf(fmaxf(s[0][0], s[0][1]), fmaxf(s[0][2], s[0][3]));
      float m1 = fmaxf(fmaxf(s[1][0], s[1][1]), fmaxf(s[1][2], s[1][3]));
      float m2 = fmaxf(fmaxf(s[2][0], s[2][1]), fmaxf(s[2][2], s[2][3]));
      float m3 = fmaxf(fmaxf(s[3][0], s[3][1]), fmaxf(s[3][2], s[3][3]));
      float lm = fmaxf(fmaxf(m0, m1), fmaxf(m2, m3));
      lm = fmaxf(lm, __shfl_xor(lm, 16));
      lm = fmaxf(lm, __shfl_xor(lm, 32));
      // deferred rescale (skip when no row's max grew)
      if (__any(lm > mrun)) {
        float mnew = fmaxf(mrun, lm);
        float c = __expf(mrun - mnew);
        mrun = mnew;
        lrun *= c;
#pragma unroll
        for (int j = 0; j < 4; ++j)
#pragma unroll
          for (int r = 0; r < 4; ++r)
            oacc[j][r] *= c;
      }
      float p[4][4];
      float ls = 0.f;
#pragma unroll
      for (int n = 0; n < 4; ++n)
#pragma unroll
        for (int r = 0; r < 4; ++r) {
          float e = __expf(s[n][r] - mrun);
          p[n][r] = e;
          ls += e;
        }
      ls += __shfl_xor(ls, 16);
      ls += __shfl_xor(ls, 32);
      lrun += ls;
      // next-tile S MFMAs: independent of softmax/PV, fills their stalls
      f32x4 sn[4] = {};
      if (!last_kb) {
#pragma unroll
        for (int n = 0; n < 4; ++n)
#pragma unroll
          for (int ks = 0; ks < 2; ++ks)
            sn[n] = __builtin_amdgcn_mfma_f32_16x16x32_bf16(kfn[n][ks], qf[ks], sn[n], 0, 0, 0);
      }
      // pack P -> bf16 fragments (register-only, no LDS)
      u32x4 pw0, pw1;
      pw0[0] = cvtpk(p[0][0], p[0][1]); pw0[1] = cvtpk(p[0][2], p[0][3]);
      pw0[2] = cvtpk(p[1][0], p[1][1]); pw0[3] = cvtpk(p[1][2], p[1][3]);
      pw1[0] = cvtpk(p[2][0], p[2][1]); pw1[1] = cvtpk(p[2][2], p[2][3]);
      pw1[2] = cvtpk(p[3][0], p[3][1]); pw1[3] = cvtpk(p[3][2], p[3][3]);
      bf16x8 pf0 = __builtin_bit_cast(bf16x8, pw0);
      bf16x8 pf1 = __builtin_bit_cast(bf16x8, pw1);
      // O^T += V^T P^T
#pragma unroll
      for (int j = 0; j < 4; ++j) {
        oacc[j] = __builtin_amdgcn_mfma_f32_16x16x32_bf16(vf[j][0], pf0, oacc[j], 0, 0, 0);
        oacc[j] = __builtin_amdgcn_mfma_f32_16x16x32_bf16(vf[j][1], pf1, oacc[j], 0, 0, 0);
      }
#pragma unroll
      for (int n = 0; n < 4; ++n) s[n] = sn[n];
    }

    // epilogue: lane holds O[q=lrow][d=j*16+lhi*4+r]
    float inv = 1.0f / lrun;
    const int t = st * 16 + lrow;
#pragma unroll
    for (int j = 0; j < 4; ++j) {
      bf16x4 ok;
#pragma unroll
      for (int r = 0; r < 4; ++r) ok[r] = f2bf(oacc[j][r] * inv);
      *(bf16x4*)(Ob + (size_t)(b * T_ + t) * D_ + h * 64 + j * 16 + lhi * 4) = ok;
    }
  }
}

extern "C" void kernel_launch(void* const* d_in, const int* in_sizes, int n_in,
                              void* d_out, int out_size, void* d_ws, size_t ws_size,
                              hipStream_t stream) {
  const float* x  = (const float*)d_in[0];
  // d_in[1] = mask (causality applied analytically)
  const float* Wq = (const float*)d_in[2];
  const float* bq = (const float*)d_in[3];
  const float* Wk = (const float*)d_in[4];
  const float* Wv = (const float*)d_in[5];
  const float* bv = (const float*)d_in[6];
  const float* Wo = (const float*)d_in[7];
  const float* bo = (const float*)d_in[8];
  float* out = (float*)d_out;

  const int MT = B_ * T_;          // 4096
  short* xb  = (short*)d_ws;                 // [4096,1024]
  short* wqb = xb  + (size_t)MT * D_;        // [1024,1024]
  short* wkb = wqb + (size_t)D_ * D_;
  short* wvb = wkb + (size_t)D_ * D_;
  short* wob = wvb + (size_t)D_ * D_;
  short* Qb  = wob + (size_t)D_ * D_;        // [B,H,T,HD]
  short* Kb  = Qb  + (size_t)MT * D_;
  short* Vtb = Kb  + (size_t)MT * D_;        // [B,H,HD,T]
  short* Ab  = Vtb + (size_t)MT * D_;        // [4096,1024]

  cast_f32_bf16<<<(MT * D_) / (256 * 8), 256, 0, stream>>>(x, xb, MT * D_);
  cast_f32_bf16<<<(D_ * D_) / (256 * 8), 256, 0, stream>>>(Wq, wqb, D_ * D_);
  cast_f32_bf16<<<(D_ * D_) / (256 * 8), 256, 0, stream>>>(Wk, wkb, D_ * D_);
  cast_f32_bf16<<<(D_ * D_) / (256 * 8), 256, 0, stream>>>(Wv, wvb, D_ * D_);
  cast_f32_bf16<<<(D_ * D_) / (256 * 8), 256, 0, stream>>>(Wo, wob, D_ * D_);

  const int grid_g = (MT / 64) * (D_ / 128);  // 512
  // Q = (x Wq^T + bq) * s^2  (s^2 = 1/sqrt(HD) = 0.125 folds both q,k scales)
  gemm_nt<<<grid_g, 256, 0, stream>>>(xb, wqb, bq, 0.125f, 0, Qb, MT, D_, D_);
  gemm_nt<<<grid_g, 256, 0, stream>>>(xb, wkb, nullptr, 1.0f, 0, Kb, MT, D_, D_);
  gemm_nt<<<grid_g, 256, 0, stream>>>(xb, wvb, bv, 1.0f, 1, Vtb, MT, D_, D_);

  attn_kernel<<<B_ * H_ * 16, 256, 0, stream>>>(Qb, Kb, Vtb, Ab);

  gemm_nt<<<grid_g, 256, 0, stream>>>(Ab, wob, bo, 1.0f, 2, out, MT, D_, D_);
}

// Round 4
// 153.528 us; speedup vs baseline: 2.4737x; 1.8259x over previous
//
#include <hip/hip_runtime.h>
#include <hip/hip_bf16.h>

#define B_ 2
#define T_ 2048
#define D_ 1024
#define H_ 16
#define HD_ 64

typedef __attribute__((ext_vector_type(8))) short bf16x8;
typedef __attribute__((ext_vector_type(4))) short bf16x4;
typedef __attribute__((ext_vector_type(4))) float f32x4;
typedef __attribute__((ext_vector_type(4))) unsigned int u32x4;

__device__ __forceinline__ short f2bf(float f) {
  unsigned int u = __builtin_bit_cast(unsigned int, f);
  u += 0x7fffu + ((u >> 16) & 1u);   // round-to-nearest-even
  return (short)(u >> 16);
}

__device__ __forceinline__ unsigned cvtpk(float lo, float hi) {
  unsigned r;
  asm("v_cvt_pk_bf16_f32 %0, %1, %2" : "=v"(r) : "v"(lo), "v"(hi));
  return r;
}

__device__ __forceinline__ void gl16(const short* g, short* l) {
  __builtin_amdgcn_global_load_lds(
      (const __attribute__((address_space(1))) void*)g,
      (__attribute__((address_space(3))) void*)l, 16, 0, 0);
}

__global__ void cast_f32_bf16(const float* __restrict__ in, short* __restrict__ out, int n) {
  int i = (blockIdx.x * blockDim.x + threadIdx.x) * 8;
  if (i + 7 >= n) return;
  float4 a = *(const float4*)(in + i);
  float4 b = *(const float4*)(in + i + 4);
  bf16x8 o;
  o[0] = f2bf(a.x); o[1] = f2bf(a.y); o[2] = f2bf(a.z); o[3] = f2bf(a.w);
  o[4] = f2bf(b.x); o[5] = f2bf(b.y); o[6] = f2bf(b.z); o[7] = f2bf(b.w);
  *(bf16x8*)(out + i) = o;
}

// C[M,N] = A[M,K] * B[N,K]^T (bf16, K-major), fp32 accum. m97-style staging:
// global_load_lds width 16 into LINEAR LDS, BM=64, BN=128, BK=64.
// mode 0: out bf16 at [b,h,t,hd]; mode 1: out bf16 at [b,h,hd,t]; mode 2: fp32 [m*N+n]
__launch_bounds__(256)
__global__ void gemm_nt(const short* __restrict__ A, const short* __restrict__ Bm,
                        const float* __restrict__ bias, float scale, int mode,
                        void* __restrict__ out, int M, int N, int K) {
  __shared__ short As[64 * 64];
  __shared__ short Bs[128 * 64];
  const int NB = N >> 7;
  const int bm = blockIdx.x / NB, bn = blockIdx.x % NB;
  const int tid = threadIdx.x, lane = tid & 63, w = tid >> 6;
  const int wr = w >> 1, wc = w & 1;
  const int lrow = lane & 15, lhi = lane >> 4;
  const int srow = lane >> 3, scol = (lane & 7) * 8;

  f32x4 acc[2][4] = {};
  const short* Ag0 = A + (size_t)(bm * 64 + w * 16 + srow) * K + scol;
  const short* Bg0 = Bm + (size_t)(bn * 128 + w * 32 + srow) * K + scol;

  for (int kt = 0; kt < K; kt += 64) {
#pragma unroll
    for (int i = 0; i < 2; ++i)
      gl16(Ag0 + kt + (size_t)i * 8 * K, As + (w * 16 + i * 8) * 64);
#pragma unroll
    for (int i = 0; i < 4; ++i)
      gl16(Bg0 + kt + (size_t)i * 8 * K, Bs + (w * 32 + i * 8) * 64);
    __syncthreads();
    bf16x8 af[2][2], bfr[2][4];
#pragma unroll
    for (int ks = 0; ks < 2; ++ks) {
#pragma unroll
      for (int i = 0; i < 2; ++i)
        af[ks][i] = *(const bf16x8*)(As + (wr * 32 + i * 16 + lrow) * 64 + ks * 32 + lhi * 8);
#pragma unroll
      for (int j = 0; j < 4; ++j)
        bfr[ks][j] = *(const bf16x8*)(Bs + (wc * 64 + j * 16 + lrow) * 64 + ks * 32 + lhi * 8);
    }
#pragma unroll
    for (int ks = 0; ks < 2; ++ks)
#pragma unroll
      for (int i = 0; i < 2; ++i)
#pragma unroll
        for (int j = 0; j < 4; ++j)
          acc[i][j] = __builtin_amdgcn_mfma_f32_16x16x32_bf16(af[ks][i], bfr[ks][j],
                                                              acc[i][j], 0, 0, 0);
    __syncthreads();
  }

#pragma unroll
  for (int i = 0; i < 2; ++i)
#pragma unroll
    for (int j = 0; j < 4; ++j) {
      const int m0 = bm * 64 + wr * 32 + i * 16 + lhi * 4;
      const int n = bn * 128 + wc * 64 + j * 16 + lrow;
      float bv = bias ? bias[n] : 0.f;
      if (mode == 1) {
        int b = m0 >> 11, t0 = m0 & 2047, h = n >> 6, hd = n & 63;
        bf16x4 ov;
#pragma unroll
        for (int r = 0; r < 4; ++r) ov[r] = f2bf((acc[i][j][r] + bv) * scale);
        *(bf16x4*)((short*)out + ((size_t)(b * H_ + h) * HD_ + hd) * T_ + t0) = ov;
      } else {
#pragma unroll
        for (int r = 0; r < 4; ++r) {
          int m = m0 + r;
          float v = (acc[i][j][r] + bv) * scale;
          if (mode == 2) {
            ((float*)out)[(size_t)m * N + n] = v;
          } else {
            int b = m >> 11, t = m & 2047, h = n >> 6, hd = n & 63;
            ((short*)out)[((size_t)(b * H_ + h) * T_ + t) * HD_ + hd] = f2bf(v);
          }
        }
      }
    }
}

// Flash attention v3: block = (bh, tile-pair (tA=s, tB=31-s)) over 64-row q-tiles.
// 4 waves each own 16 q-rows of BOTH tiles; K/V tiles staged once per block in
// LDS (XOR-swizzled, double-buffered, global_load_lds w16, issue-early).
// XCD swizzle: all 16 blocks of a bh land on one XCD (K/V L2-resident).
// S^T = mfma(K,Q); register-only P via custom PV k-slot bijection.
__launch_bounds__(256, 2)
__global__ void attn_kernel(const short* __restrict__ Q, const short* __restrict__ K,
                            const short* __restrict__ Vt, short* __restrict__ Ob) {
  __shared__ short Ks_[2][64 * 64];
  __shared__ short Vs_[2][64 * 64];
  const int tid = threadIdx.x, lane = tid & 63, w = tid >> 6;
  const int lrow = lane & 15, lhi = lane >> 4;
  const int bid = blockIdx.x;
  const int bh = (bid & 7) * 4 + ((bid >> 3) & 3);   // 4 bh per XCD
  const int s  = bid >> 5;                            // 0..15 pair index
  const int tA = s, tB = 31 - s;
  const int b = bh >> 4, h = bh & 15;
  const short* Kbh = K + (size_t)bh * T_ * HD_;
  const short* Vbh = Vt + (size_t)bh * HD_ * T_;

  bf16x8 qfA[2], qfB[2];
#pragma unroll
  for (int ks = 0; ks < 2; ++ks) {
    qfA[ks] = *(const bf16x8*)(Q + ((size_t)bh * T_ + tA * 64 + w * 16 + lrow) * HD_ + ks * 32 + lhi * 8);
    qfB[ks] = *(const bf16x8*)(Q + ((size_t)bh * T_ + tB * 64 + w * 16 + lrow) * HD_ + ks * 32 + lhi * 8);
  }

  const int srow8 = lane >> 3, sch = lane & 7;
  f32x4 oaccA[4] = {}, oaccB[4] = {};
  float mrunA = -3e38f, lrunA = 0.f, mrunB = -3e38f, lrunB = 0.f;
  const int qlocal = w * 16 + lrow;
  const int swz = (lrow & 7) << 3;     // element-space XOR for reads

  // stage K/V tile kb into buf: LDS linear dest, pre-swizzled global source
  auto STAGE = [&](int kb, int buf) {
#pragma unroll
    for (int pass = 0; pass < 2; ++pass) {
      int row = pass * 32 + w * 8 + srow8;
      int csrc = (sch ^ (row & 7)) * 8;
      gl16(Kbh + (size_t)(kb * 64 + row) * HD_ + csrc, &Ks_[buf][(pass * 32 + w * 8) * 64]);
      gl16(Vbh + (size_t)row * T_ + kb * 64 + csrc, &Vs_[buf][(pass * 32 + w * 8) * 64]);
    }
  };

  // softmax + PV for one tile (vf captured)
  bf16x8 vf[4][2];
  auto smpv = [&](f32x4* sv, float& mrun, float& lrun, f32x4* oacc) {
    float lm = fmaxf(fmaxf(fmaxf(sv[0][0], sv[0][1]), fmaxf(sv[0][2], sv[0][3])),
               fmaxf(fmaxf(fmaxf(sv[1][0], sv[1][1]), fmaxf(sv[1][2], sv[1][3])),
               fmaxf(fmaxf(fmaxf(sv[2][0], sv[2][1]), fmaxf(sv[2][2], sv[2][3])),
                     fmaxf(fmaxf(sv[3][0], sv[3][1]), fmaxf(sv[3][2], sv[3][3])))));
    lm = fmaxf(lm, __shfl_xor(lm, 16));
    lm = fmaxf(lm, __shfl_xor(lm, 32));
    if (__any(lm > mrun)) {
      float mnew = fmaxf(mrun, lm);
      float c = __expf(mrun - mnew);
      mrun = mnew;
      lrun *= c;
#pragma unroll
      for (int j = 0; j < 4; ++j)
#pragma unroll
        for (int r = 0; r < 4; ++r)
          oacc[j][r] *= c;
    }
    float p[4][4];
    float ls = 0.f;
#pragma unroll
    for (int n = 0; n < 4; ++n)
#pragma unroll
      for (int r = 0; r < 4; ++r) {
        float e = __expf(sv[n][r] - mrun);
        p[n][r] = e;
        ls += e;
      }
    ls += __shfl_xor(ls, 16);
    ls += __shfl_xor(ls, 32);
    lrun += ls;
    u32x4 pw0, pw1;
    pw0[0] = cvtpk(p[0][0], p[0][1]); pw0[1] = cvtpk(p[0][2], p[0][3]);
    pw0[2] = cvtpk(p[1][0], p[1][1]); pw0[3] = cvtpk(p[1][2], p[1][3]);
    pw1[0] = cvtpk(p[2][0], p[2][1]); pw1[1] = cvtpk(p[2][2], p[2][3]);
    pw1[2] = cvtpk(p[3][0], p[3][1]); pw1[3] = cvtpk(p[3][2], p[3][3]);
    bf16x8 pf0 = __builtin_bit_cast(bf16x8, pw0);
    bf16x8 pf1 = __builtin_bit_cast(bf16x8, pw1);
#pragma unroll
    for (int j = 0; j < 4; ++j) {
      oacc[j] = __builtin_amdgcn_mfma_f32_16x16x32_bf16(vf[j][0], pf0, oacc[j], 0, 0, 0);
      oacc[j] = __builtin_amdgcn_mfma_f32_16x16x32_bf16(vf[j][1], pf1, oacc[j], 0, 0, 0);
    }
  };

  STAGE(0, 0);
  int cur = 0;
  for (int kb = 0; kb <= tB; ++kb) {
    asm volatile("s_waitcnt vmcnt(0) lgkmcnt(0)" ::: "memory");
    __builtin_amdgcn_s_barrier();
    asm volatile("" ::: "memory");
    const short* Kc = Ks_[cur];
    const short* Vc = Vs_[cur];
    // K fragments (swizzled b128 reads)
    bf16x8 kf[4][2];
#pragma unroll
    for (int n = 0; n < 4; ++n)
#pragma unroll
      for (int ks = 0; ks < 2; ++ks)
        kf[n][ks] = *(const bf16x8*)(Kc + (n * 16 + lrow) * 64 + ((ks * 32 + lhi * 8) ^ swz));
    // V fragments with PV k-slot bijection: k = (2ks+(e>>2))*16 + lhi*4 + (e&3)
#pragma unroll
    for (int j = 0; j < 4; ++j)
#pragma unroll
      for (int ks = 0; ks < 2; ++ks) {
        bf16x4 lo = *(const bf16x4*)(Vc + (j * 16 + lrow) * 64 + ((ks * 32 + lhi * 4) ^ swz));
        bf16x4 hi = *(const bf16x4*)(Vc + (j * 16 + lrow) * 64 + ((ks * 32 + 16 + lhi * 4) ^ swz));
        bf16x8 v;
        v[0] = lo[0]; v[1] = lo[1]; v[2] = lo[2]; v[3] = lo[3];
        v[4] = hi[0]; v[5] = hi[1]; v[6] = hi[2]; v[7] = hi[3];
        vf[j][ks] = v;
      }
    // issue next tile's staging now; its latency hides under compute below
    if (kb < tB) STAGE(kb + 1, cur ^ 1);

    // S^T for tile B (always) and tile A (while kb <= tA)
    f32x4 sB[4] = {};
#pragma unroll
    for (int n = 0; n < 4; ++n)
#pragma unroll
      for (int ks = 0; ks < 2; ++ks)
        sB[n] = __builtin_amdgcn_mfma_f32_16x16x32_bf16(kf[n][ks], qfB[ks], sB[n], 0, 0, 0);
    const bool actA = (kb <= tA);
    f32x4 sA[4] = {};
    if (actA) {
#pragma unroll
      for (int n = 0; n < 4; ++n)
#pragma unroll
        for (int ks = 0; ks < 2; ++ks)
          sA[n] = __builtin_amdgcn_mfma_f32_16x16x32_bf16(kf[n][ks], qfA[ks], sA[n], 0, 0, 0);
    }
    // causal masks on diagonal iterations (local coords)
    if (kb == tB) {
#pragma unroll
      for (int n = 0; n < 4; ++n)
#pragma unroll
        for (int r = 0; r < 4; ++r)
          if (n * 16 + lhi * 4 + r > qlocal) sB[n][r] = -1e9f;
    }
    if (kb == tA) {
#pragma unroll
      for (int n = 0; n < 4; ++n)
#pragma unroll
        for (int r = 0; r < 4; ++r)
          if (n * 16 + lhi * 4 + r > qlocal) sA[n][r] = -1e9f;
    }
    smpv(sB, mrunB, lrunB, oaccB);
    if (actA) smpv(sA, mrunA, lrunA, oaccA);
    cur ^= 1;
  }

  // epilogue: lane holds O^T[d = j*16+lhi*4+r][q = lrow] per tile
  float invA = 1.0f / lrunA, invB = 1.0f / lrunB;
  const int tAq = tA * 64 + qlocal, tBq = tB * 64 + qlocal;
#pragma unroll
  for (int j = 0; j < 4; ++j) {
    bf16x4 oA, oB;
#pragma unroll
    for (int r = 0; r < 4; ++r) {
      oA[r] = f2bf(oaccA[j][r] * invA);
      oB[r] = f2bf(oaccB[j][r] * invB);
    }
    *(bf16x4*)(Ob + (size_t)(b * T_ + tAq) * D_ + h * 64 + j * 16 + lhi * 4) = oA;
    *(bf16x4*)(Ob + (size_t)(b * T_ + tBq) * D_ + h * 64 + j * 16 + lhi * 4) = oB;
  }
}

extern "C" void kernel_launch(void* const* d_in, const int* in_sizes, int n_in,
                              void* d_out, int out_size, void* d_ws, size_t ws_size,
                              hipStream_t stream) {
  const float* x  = (const float*)d_in[0];
  // d_in[1] = mask (causality applied analytically)
  const float* Wq = (const float*)d_in[2];
  const float* bq = (const float*)d_in[3];
  const float* Wk = (const float*)d_in[4];
  const float* Wv = (const float*)d_in[5];
  const float* bv = (const float*)d_in[6];
  const float* Wo = (const float*)d_in[7];
  const float* bo = (const float*)d_in[8];
  float* out = (float*)d_out;

  const int MT = B_ * T_;          // 4096
  short* xb  = (short*)d_ws;                 // [4096,1024]
  short* wqb = xb  + (size_t)MT * D_;        // [1024,1024]
  short* wkb = wqb + (size_t)D_ * D_;
  short* wvb = wkb + (size_t)D_ * D_;
  short* wob = wvb + (size_t)D_ * D_;
  short* Qb  = wob + (size_t)D_ * D_;        // [B,H,T,HD]
  short* Kb  = Qb  + (size_t)MT * D_;
  short* Vtb = Kb  + (size_t)MT * D_;        // [B,H,HD,T]
  short* Ab  = Vtb + (size_t)MT * D_;        // [4096,1024]

  cast_f32_bf16<<<(MT * D_) / (256 * 8), 256, 0, stream>>>(x, xb, MT * D_);
  cast_f32_bf16<<<(D_ * D_) / (256 * 8), 256, 0, stream>>>(Wq, wqb, D_ * D_);
  cast_f32_bf16<<<(D_ * D_) / (256 * 8), 256, 0, stream>>>(Wk, wkb, D_ * D_);
  cast_f32_bf16<<<(D_ * D_) / (256 * 8), 256, 0, stream>>>(Wv, wvb, D_ * D_);
  cast_f32_bf16<<<(D_ * D_) / (256 * 8), 256, 0, stream>>>(Wo, wob, D_ * D_);

  const int grid_g = (MT / 64) * (D_ / 128);  // 512
  // Q = (x Wq^T + bq) * s^2  (s^2 = 1/sqrt(HD) = 0.125 folds both q,k scales)
  gemm_nt<<<grid_g, 256, 0, stream>>>(xb, wqb, bq, 0.125f, 0, Qb, MT, D_, D_);
  gemm_nt<<<grid_g, 256, 0, stream>>>(xb, wkb, nullptr, 1.0f, 0, Kb, MT, D_, D_);
  gemm_nt<<<grid_g, 256, 0, stream>>>(xb, wvb, bv, 1.0f, 1, Vtb, MT, D_, D_);

  attn_kernel<<<B_ * H_ * 16, 256, 0, stream>>>(Qb, Kb, Vtb, Ab);

  gemm_nt<<<grid_g, 256, 0, stream>>>(Ab, wob, bo, 1.0f, 2, out, MT, D_, D_);
}